// Round 1
// 153.778 us; speedup vs baseline: 1.0064x; 1.0064x over previous
//
#include <hip/hip_runtime.h>

#define B_    4
#define N_    2048
#define HID_  768
#define NH_   12
#define E_    131072
#define M_    8192   // B_*N_
#define NREL_ 64
#define G_    16     // groups per attn block
#define BAND_ 32     // band width (K/V rows per block)
#define VP_   40     // Vt pitch in u16 (32 slots + 8 pad): 16B-aligned frags, spread banks
#define PP_   40     // p_bf pitch in u16

typedef unsigned short u16;
typedef unsigned int   u32;
typedef short bf16x8 __attribute__((ext_vector_type(8)));
typedef float f32x4  __attribute__((ext_vector_type(4)));

__device__ __forceinline__ u16 f2bf(float x) {
  u32 u = __float_as_uint(x);
  u += 0x7fffu + ((u >> 16) & 1u);   // RNE
  return (u16)(u >> 16);
}
__device__ __forceinline__ float bflo(u32 u) { return __uint_as_float(u << 16); }
__device__ __forceinline__ float bfhi(u32 u) { return __uint_as_float(u & 0xffff0000u); }
__device__ __forceinline__ float bf1(u16 v) { return __uint_as_float(((u32)v) << 16); }

__device__ __forceinline__ void load_lds16(const u16* g, u16* l) {
  __builtin_amdgcn_global_load_lds((__attribute__((address_space(1))) void*)(g),
                                   (__attribute__((address_space(3))) void*)(l),
                                   16, 0, 0);
}

// ---------------- Kernel 0: f32 -> bf16 convert (X, Wq, Wk, Wv, rel) ----------------
// HBM-roofline for its ~47MB of traffic. Frozen.
__global__ __launch_bounds__(256) void k_convert(
    const float4* __restrict__ X, const float4* __restrict__ Wq,
    const float4* __restrict__ Wk, const float4* __restrict__ Wv,
    const float4* __restrict__ rel,
    ushort4* __restrict__ Xbf, ushort4* __restrict__ Wbf, ushort4* __restrict__ Rbf) {
  const int NX4 = (M_ * HID_) / 4;
  const int NW4 = (HID_ * HID_) / 4;
  const int NR4 = (NREL_ * HID_) / 4;
  int tid = blockIdx.x * 256 + threadIdx.x;
  const float4* src; ushort4* dst; int off;
  if (tid < NX4) { src = X; dst = Xbf; off = tid; }
  else if (tid < NX4 + 3 * NW4) {
    int t2 = tid - NX4;
    int wi = t2 / NW4;
    off = t2 - wi * NW4;
    src = (wi == 0) ? Wq : (wi == 1) ? Wk : Wv;
    dst = Wbf + (size_t)wi * NW4;
  } else {
    off = tid - NX4 - 3 * NW4;
    if (off >= NR4) return;
    src = rel; dst = Rbf;
  }
  float4 v = src[off];
  ushort4 o;
  o.x = f2bf(v.x); o.y = f2bf(v.y); o.z = f2bf(v.z); o.w = f2bf(v.w);
  dst[off] = o;
}

// ---------------- Kernel 1: fused QKV GEMM, counted-vmcnt triple-buffer pipeline ----
// R9 restructure: BM=256 x BN=288 (fused N=2304 across Q|K|V), BK=32, 512 threads,
// 8 waves as 4x2 -> wave tile 64x144 (4x9 frags; 0.0295 LDS-B/FLOP -> ~1.7PF LDS cap).
// Grid 32x8 = 256 blocks = EXACTLY one balanced round at 1 block/CU (104KB LDS).
// Per K-tile: ONE s_barrier + ONE counted s_waitcnt vmcnt(5|4) (never 0 until the
// last tile); tile t+2 staged into buf (t+2)%3 while computing t -> no drain stall.
__global__ __launch_bounds__(512, 2) void k_gemm(
    const u16* __restrict__ Xbf, const u16* __restrict__ Wbf,
    const float* __restrict__ bq, const float* __restrict__ bk, const float* __restrict__ bv,
    u16* __restrict__ Qb, u16* __restrict__ Kb, u16* __restrict__ Vb) {
  extern __shared__ __align__(16) u16 lds[];   // [3][256*32] A  + [3][288*32] B = 104448B
  const int tid = threadIdx.x;
  const int w = tid >> 6, lane = tid & 63;
  const int lm = lane & 15, lg = lane >> 4;
  const int wm = w >> 1, wn = w & 1;           // 4x2 wave grid
  const int m0  = blockIdx.x * 256;
  const int n0g = blockIdx.y * 288;            // fused col base (0..2303)

  f32x4 acc[4][9] = {};

  // Stage tile kt (cols kt*32..+31) into buffer bi. Linear LDS dest (global_load_lds),
  // source col pre-swizzled by involution g ^= (row>>1)&3 -> 2-way banks on b128 reads.
  auto STAGE = [&](int bi, int kt) {
    const int k0 = kt * 32;
    u16* Ab = lds + bi * (256 * 32);
    u16* Bb = lds + 3 * (256 * 32) + bi * (288 * 32);
#pragma unroll
    for (int ii = 0; ii < 2; ++ii) {           // A: 1024 16B-chunks = 2/thread
      const int sb = (ii * 8 + w) * 64;
      const int s  = sb + lane;
      const int m  = s >> 2;
      const int g  = (s & 3) ^ ((m >> 1) & 3);
      load_lds16(Xbf + (size_t)(m0 + m) * HID_ + k0 + g * 8, Ab + sb * 8);
    }
#pragma unroll
    for (int ii = 0; ii < 2; ++ii) {           // B: 1152 chunks = 2/thread + tail
      const int sb = (ii * 8 + w) * 64;
      const int s  = sb + lane;
      const int m  = s >> 2;
      const int g  = (s & 3) ^ ((m >> 1) & 3);
      load_lds16(Wbf + (size_t)(n0g + m) * HID_ + k0 + g * 8, Bb + sb * 8);
    }
    if (w < 2) {                               // tail: rows 256..287 (waves 0,1 only)
      const int sb = (16 + w) * 64;
      const int s  = sb + lane;
      const int m  = s >> 2;
      const int g  = (s & 3) ^ ((m >> 1) & 3);
      load_lds16(Wbf + (size_t)(n0g + m) * HID_ + k0 + g * 8, Bb + sb * 8);
    }
  };

  auto COMPUTE = [&](int bi) {
    const u16* As = lds + bi * (256 * 32);
    const u16* Bs = lds + 3 * (256 * 32) + bi * (288 * 32);
    bf16x8 bfv[9];
#pragma unroll
    for (int nt = 0; nt < 9; ++nt) {
      const int n = wn * 144 + nt * 16 + lm;
      const int g = lg ^ ((n >> 1) & 3);
      bfv[nt] = *(const bf16x8*)&Bs[n * 32 + g * 8];
    }
    __builtin_amdgcn_s_setprio(1);
#pragma unroll
    for (int mt = 0; mt < 4; ++mt) {
      const int m = wm * 64 + mt * 16 + lm;
      const int g = lg ^ ((m >> 1) & 3);
      bf16x8 af = *(const bf16x8*)&As[m * 32 + g * 8];
#pragma unroll
      for (int nt = 0; nt < 9; ++nt)
        acc[mt][nt] = __builtin_amdgcn_mfma_f32_16x16x32_bf16(af, bfv[nt], acc[mt][nt], 0, 0, 0);
    }
    __builtin_amdgcn_s_setprio(0);
  };

  // Per-wave stage load count: waves 0,1 issue 5 global_load_lds per tile, others 4.
  // Boundary wait leaves exactly one tile's loads (the newest) in flight.
#define BODYK(KT, BC, BS, DOSTAGE, VMZ)                                  \
  do {                                                                   \
    if (VMZ)        asm volatile("s_waitcnt vmcnt(0)" ::: "memory");     \
    else if (w < 2) asm volatile("s_waitcnt vmcnt(5)" ::: "memory");     \
    else            asm volatile("s_waitcnt vmcnt(4)" ::: "memory");     \
    __builtin_amdgcn_s_barrier();                                        \
    asm volatile("" ::: "memory");                                       \
    if (DOSTAGE) STAGE(BS, (KT) + 2);                                    \
    COMPUTE(BC);                                                         \
  } while (0)

  STAGE(0, 0);
  STAGE(1, 1);
  for (int t3 = 0; t3 < 21; t3 += 3) {     // kt = 0..20
    BODYK(t3 + 0, 0, 2, true, false);
    BODYK(t3 + 1, 1, 0, true, false);
    BODYK(t3 + 2, 2, 1, true, false);
  }
  BODYK(21, 0, 2, true,  false);           // stages tile 23
  BODYK(22, 1, 0, false, false);
  BODYK(23, 2, 1, false, true);            // final tile: full drain
#undef BODYK

  // Epilogue: fused col -> (widx, local col). 16-col runs never straddle a 768
  // boundary (all bases multiple of 16), so widx is uniform per (nt) fragment.
#pragma unroll
  for (int nt = 0; nt < 9; ++nt) {
    const int c    = n0g + wn * 144 + nt * 16 + lm;
    const int widx = (c >= 1536) ? 2 : (c >= 768) ? 1 : 0;
    const int col  = c - widx * 768;
    const float bb = ((widx == 0) ? bq : (widx == 1) ? bk : bv)[col];
    u16* Op = (widx == 0) ? Qb : (widx == 1) ? Kb : Vb;
#pragma unroll
    for (int mt = 0; mt < 4; ++mt) {
      const int rbase = m0 + wm * 64 + mt * 16 + lg * 4;
#pragma unroll
      for (int r = 0; r < 4; ++r)
        Op[(size_t)(rbase + r) * HID_ + col] = f2bf(acc[mt][nt][r] + bb);
    }
  }
}

// ---------------- Kernel 1b: QRel[(b,i)][h*64+r] = Q[b,i,h,:]·rel[r,h,:] ----------------
__global__ __launch_bounds__(256) void k_qrel(
    const u16* __restrict__ Qb, const u16* __restrict__ Rbf, u16* __restrict__ QRelb) {
  const int tid = threadIdx.x, w = tid >> 6, lane = tid & 63;
  const int lm = lane & 15, quad = lane >> 4;
  const int m0 = blockIdx.x * 32 + (w & 1) * 16;
  const int h0 = (w >> 1) * 6;
#pragma unroll
  for (int hh = 0; hh < 6; ++hh) {
    const int h = h0 + hh;
    const u16* qp = Qb + (size_t)(m0 + lm) * HID_ + h * 64 + quad * 8;
    bf16x8 a0 = *(const bf16x8*)(qp);
    bf16x8 a1 = *(const bf16x8*)(qp + 32);
#pragma unroll
    for (int rt = 0; rt < 4; ++rt) {
      const u16* rp = Rbf + (size_t)(rt * 16 + lm) * HID_ + h * 64 + quad * 8;
      bf16x8 b0 = *(const bf16x8*)(rp);
      bf16x8 b1 = *(const bf16x8*)(rp + 32);
      f32x4 c = {0.f, 0.f, 0.f, 0.f};
      c = __builtin_amdgcn_mfma_f32_16x16x32_bf16(a0, b0, c, 0, 0, 0);
      c = __builtin_amdgcn_mfma_f32_16x16x32_bf16(a1, b1, c, 0, 0, 0);
#pragma unroll
      for (int r = 0; r < 4; ++r)
        QRelb[(size_t)(m0 + quad * 4 + r) * HID_ + h * 64 + rt * 16 + lm] = f2bf(c[r]);
    }
  }
}

// ---------------- Kernel 2: banded attention, single-window 2-barrier ----------------
// R8 restructure: no K LDS staging at all. Heads partition the dims, so each
// (K-row, 16B dim-chunk) is consumed by exactly one (wave, head): lanes load
// their QK B-fragments DIRECTLY from global (same total bytes as staging,
// zero LDS round-trip). All global loads (V rows -> 48 VGPR, K frags -> 72,
// Q frags -> 24) issue before barrier A, which also publishes r_s/t_s/badf/
// p_bf-zero -> ONE vmcnt drain for the whole kernel. After barrier A all data
// is in registers: Vt scatter + QK MFMA + softmax -> p_bf, barrier B, PV MFMA.
__global__ __launch_bounds__(256, 2) void k_attn(
    const u16* __restrict__ Qb, const u16* __restrict__ Kb, const u16* __restrict__ Vb,
    const u16* __restrict__ QRelb, const int* __restrict__ eidx,
    float* __restrict__ out) {
  __shared__ __align__(16) u16 Vt[HID_ * VP_];       // 61,440B
  __shared__ __align__(16) u16 p_bf[NH_ * 16 * PP_]; // 15,360B
  __shared__ u16 r_s[256];
  __shared__ int t_s[256];
  __shared__ int badf;

  const int tid = threadIdx.x;
  const int w = tid >> 6, lane = tid & 63;
  const int lm = lane & 15, quad = lane >> 4;
  const int e0b = blockIdx.x * 256;
  const int b  = eidx[e0b];
  const int i0 = eidx[E_ + e0b];
  const int bN = b * N_;

  // ---- V prefetch into VGPRs (48 VGPR), transpose-store mapping ----
  const int sV = tid & 31, pV = tid >> 5;
  const int rowV = (i0 + 1 + sV) & (N_ - 1);
  const u16* srcV = Vb + (size_t)(bN + rowV) * HID_ + pV * 96;
  uint4 vv[12];
#pragma unroll
  for (int c = 0; c < 12; ++c) vv[c] = *(const uint4*)(srcV + c * 8);

  // ---- Q + K fragments direct from global (B-frag layout, 16B/lane) ----
  const u16* Qrow  = Qb + (size_t)(bN + i0 + lm) * HID_ + quad * 8;
  const u16* Krow0 = Kb + (size_t)(bN + ((i0 + 1 + lm) & (N_ - 1))) * HID_ + quad * 8;
  const u16* Krow1 = Kb + (size_t)(bN + ((i0 + 17 + lm) & (N_ - 1))) * HID_ + quad * 8;
  bf16x8 qa[3][2], ka[3][4];
#pragma unroll
  for (int hh = 0; hh < 3; ++hh) {
    const int o = (w * 3 + hh) * 64;
    qa[hh][0] = *(const bf16x8*)(Qrow + o);
    qa[hh][1] = *(const bf16x8*)(Qrow + o + 32);
    ka[hh][0] = *(const bf16x8*)(Krow0 + o);
    ka[hh][1] = *(const bf16x8*)(Krow0 + o + 32);
    ka[hh][2] = *(const bf16x8*)(Krow1 + o);
    ka[hh][3] = *(const bf16x8*)(Krow1 + o + 32);
  }

  // ---- P0: publish t/r, zero p_bf, band-pattern check ----
  const int t_own = eidx[2 * E_ + e0b + tid];
  const int r_own = eidx[3 * E_ + e0b + tid];
  t_s[tid] = t_own;
  r_s[tid] = (u16)r_own;
  if (tid == 0) badf = 0;
  {
    u32* pz = (u32*)p_bf;
#pragma unroll
    for (int z = 0; z < NH_ * 16 * PP_ / 2 / 256; ++z) pz[z * 256 + tid] = 0;
    const int expect = (i0 + (tid >> 4) + (tid & 15) + 1) & (N_ - 1);
    if (t_own != expect) badf = 1;
  }
  __syncthreads();   // barrier A: publishes LDS + drains ALL global loads
  const int bad = badf;

  if (!bad) {
    // ---- Vt scatter from registers (2-way banks, free) ----
#pragma unroll
    for (int c = 0; c < 12; ++c) {
      uint4 v = vv[c];
      const int d0 = pV * 96 + c * 8;
      Vt[(d0 + 0) * VP_ + sV] = (u16)(v.x);
      Vt[(d0 + 1) * VP_ + sV] = (u16)(v.x >> 16);
      Vt[(d0 + 2) * VP_ + sV] = (u16)(v.y);
      Vt[(d0 + 3) * VP_ + sV] = (u16)(v.y >> 16);
      Vt[(d0 + 4) * VP_ + sV] = (u16)(v.z);
      Vt[(d0 + 5) * VP_ + sV] = (u16)(v.z >> 16);
      Vt[(d0 + 6) * VP_ + sV] = (u16)(v.w);
      Vt[(d0 + 7) * VP_ + sV] = (u16)(v.w >> 16);
    }

    // ---- QRel gather (r_s now visible; L2-resident) ----
    int eidx4[4]; float qrelv[3][4];
#pragma unroll
    for (int r = 0; r < 4; ++r) {
      const int il = quad * 4 + r;
      eidx4[r] = il * 16 + ((lm - il) & 15);
    }
#pragma unroll
    for (int hh = 0; hh < 3; ++hh) {
      const int h = w * 3 + hh;
#pragma unroll
      for (int r = 0; r < 4; ++r) {
        const int il = quad * 4 + r;
        qrelv[hh][r] = bf1(QRelb[(size_t)(bN + i0 + il) * HID_ + h * 64 + r_s[eidx4[r]]]);
      }
    }

    // ---- QK^T MFMA (all-register operands) + in-register softmax -> p_bf ----
#pragma unroll
    for (int hh = 0; hh < 3; ++hh) {
      const int h = w * 3 + hh;
      f32x4 c0 = {0.f, 0.f, 0.f, 0.f}, c1 = {0.f, 0.f, 0.f, 0.f};
      c0 = __builtin_amdgcn_mfma_f32_16x16x32_bf16(qa[hh][0], ka[hh][0], c0, 0, 0, 0);
      c0 = __builtin_amdgcn_mfma_f32_16x16x32_bf16(qa[hh][1], ka[hh][1], c0, 0, 0, 0);
      c1 = __builtin_amdgcn_mfma_f32_16x16x32_bf16(qa[hh][0], ka[hh][2], c1, 0, 0, 0);
      c1 = __builtin_amdgcn_mfma_f32_16x16x32_bf16(qa[hh][1], ka[hh][3], c1, 0, 0, 0);
#pragma unroll
      for (int r = 0; r < 4; ++r) {
        const int il = quad * 4 + r;
        const float val = (lm >= il) ? c0[r] : c1[r];
        const float ex = __expf((val - qrelv[hh][r]) * 0.125f);
        float den = ex;
        den += __shfl_xor(den, 1);
        den += __shfl_xor(den, 2);
        den += __shfl_xor(den, 4);
        den += __shfl_xor(den, 8);
        const float p = ex * __builtin_amdgcn_rcpf(den);
        const int slot = il + ((lm - il) & 15);
        p_bf[(h * 16 + il) * PP_ + slot] = f2bf(p);
      }
    }
    __syncthreads();   // barrier B: Vt + p_bf complete

    // ---- PV: out = P @ Vband via MFMA ----
#pragma unroll
    for (int hh = 0; hh < 3; ++hh) {
      const int h = w * 3 + hh;
      bf16x8 af = *(const bf16x8*)&p_bf[(h * 16 + lm) * PP_ + quad * 8];
#pragma unroll
      for (int nt = 0; nt < 4; ++nt) {
        bf16x8 bv = *(const bf16x8*)&Vt[(h * 64 + nt * 16 + lm) * VP_ + quad * 8];
        f32x4 d = {0.f, 0.f, 0.f, 0.f};
        d = __builtin_amdgcn_mfma_f32_16x16x32_bf16(af, bv, d, 0, 0, 0);
#pragma unroll
        for (int r = 0; r < 4; ++r)
          out[(size_t)(bN + i0 + quad * 4 + r) * HID_ + h * 64 + nt * 16 + lm] = d[r];
      }
    }
  } else {
    // ---- Fallback (block-uniform; never taken for reference edge pattern) ----
    const int il = tid >> 4;
#pragma unroll
    for (int h = 0; h < NH_; ++h) {
      const u16* qp = Qb + (size_t)(bN + i0 + il) * HID_ + h * 64;
      const u16* kp = Kb + (size_t)(bN + t_own) * HID_ + h * 64;
      float s = 0.f;
      for (int d = 0; d < 64; ++d) s += bf1(qp[d]) * bf1(kp[d]);
      const float qrel = bf1(QRelb[(size_t)(bN + i0 + il) * HID_ + h * 64 + r_own]);
      const float ex = __expf((s - qrel) * 0.125f);
      float den = ex;
      den += __shfl_xor(den, 1);
      den += __shfl_xor(den, 2);
      den += __shfl_xor(den, 4);
      den += __shfl_xor(den, 8);
      p_bf[tid * NH_ + h] = f2bf(ex * __builtin_amdgcn_rcpf(den));
    }
    __syncthreads();
#pragma unroll
    for (int gsub = 0; gsub < 4; ++gsub) {
      const int il2 = w * 4 + gsub;
      float a0[8] = {0.f,0.f,0.f,0.f,0.f,0.f,0.f,0.f};
      float a1[8] = {0.f,0.f,0.f,0.f,0.f,0.f,0.f,0.f};
      for (int j2 = 0; j2 < 16; ++j2) {
        const int t2 = t_s[il2 * 16 + j2];
        const u16* Vrow = Vb + (size_t)(bN + t2) * HID_;
        uint4 v0 = *(const uint4*)(Vrow + lane * 8);
        const float p0 = bf1(p_bf[(il2 * 16 + j2) * NH_ + (lane >> 3)]);
        a0[0] += p0 * bflo(v0.x); a0[1] += p0 * bfhi(v0.x);
        a0[2] += p0 * bflo(v0.y); a0[3] += p0 * bfhi(v0.y);
        a0[4] += p0 * bflo(v0.z); a0[5] += p0 * bfhi(v0.z);
        a0[6] += p0 * bflo(v0.w); a0[7] += p0 * bfhi(v0.w);
        if (lane < 32) {
          uint4 v1 = *(const uint4*)(Vrow + 512 + lane * 8);
          const float p1 = bf1(p_bf[(il2 * 16 + j2) * NH_ + 8 + (lane >> 3)]);
          a1[0] += p1 * bflo(v1.x); a1[1] += p1 * bfhi(v1.x);
          a1[2] += p1 * bflo(v1.y); a1[3] += p1 * bfhi(v1.y);
          a1[4] += p1 * bflo(v1.z); a1[5] += p1 * bfhi(v1.z);
          a1[6] += p1 * bflo(v1.w); a1[7] += p1 * bfhi(v1.w);
        }
      }
      float* orow = out + (size_t)(bN + i0 + il2) * HID_;
      *(float4*)(orow + lane * 8)     = make_float4(a0[0], a0[1], a0[2], a0[3]);
      *(float4*)(orow + lane * 8 + 4) = make_float4(a0[4], a0[5], a0[6], a0[7]);
      if (lane < 32) {
        *(float4*)(orow + 512 + lane * 8)     = make_float4(a1[0], a1[1], a1[2], a1[3]);
        *(float4*)(orow + 512 + lane * 8 + 4) = make_float4(a1[4], a1[5], a1[6], a1[7]);
      }
    }
  }
}

extern "C" void kernel_launch(void* const* d_in, const int* in_sizes, int n_in,
                              void* d_out, int out_size, void* d_ws, size_t ws_size,
                              hipStream_t stream) {
  const float* X   = (const float*)d_in[0];
  const int*   eidx= (const int*)d_in[1];
  const float* Wq  = (const float*)d_in[2];
  const float* bq  = (const float*)d_in[3];
  const float* Wk  = (const float*)d_in[4];
  const float* bk  = (const float*)d_in[5];
  const float* Wv  = (const float*)d_in[6];
  const float* bv  = (const float*)d_in[7];
  const float* rel = (const float*)d_in[8];
  float* out = (float*)d_out;

  char* ws = (char*)d_ws;
  u16* Xbf = (u16*)(ws);
  u16* QRelb = Xbf;                       // overlays Xbf (dead after k_gemm)
  u16* Wbf = (u16*)(ws + 12582912);
  u16* Qb  = (u16*)(ws + 16121856);
  u16* Kb  = (u16*)(ws + 28704768);
  u16* Vb  = (u16*)(ws + 41287680);
  u16* Rbf = (u16*)(ws + 53870592);

  static bool s_attr = false;
  if (!s_attr) {
    (void)hipFuncSetAttribute((const void*)k_gemm,
                              hipFuncAttributeMaxDynamicSharedMemorySize, 104448);
    s_attr = true;
  }

  k_convert<<<7920, 256, 0, stream>>>((const float4*)X, (const float4*)Wq,
                                      (const float4*)Wk, (const float4*)Wv,
                                      (const float4*)rel,
                                      (ushort4*)Xbf, (ushort4*)Wbf, (ushort4*)Rbf);
  k_gemm<<<dim3(32, 8), 512, 104448, stream>>>(Xbf, Wbf, bq, bk, bv, Qb, Kb, Vb);
  k_qrel<<<256, 256, 0, stream>>>(Qb, Rbf, QRelb);
  k_attn<<<512, 256, 0, stream>>>(Qb, Kb, Vb, QRelb, eidx, out);
}